// Round 5
// baseline (286.659 us; speedup 1.0000x reference)
//
#include <hip/hip_runtime.h>
#include <hip/hip_bf16.h>
#include <cstdint>

typedef unsigned int uint;
typedef unsigned short ushort_t;

typedef __attribute__((ext_vector_type(8))) short short8;
typedef __attribute__((ext_vector_type(4))) short short4_t;
typedef __attribute__((ext_vector_type(4))) float float4_t;

#define NEMBD 1024
#define VOCAB 32000
#define LOG2E 1.4426950408889634f

__device__ __forceinline__ ushort_t f2bf_rne(float f) {
    uint u = __float_as_uint(f);
    u += 0x7fffu + ((u >> 16) & 1u);
    return (ushort_t)(u >> 16);
}

// K1a: ST[v*32+h] = bf16(sum_d ve[v, h*32+d]). Block per vocab row, coalesced.
__global__ void k_build_st(const float* __restrict__ ve, ushort_t* __restrict__ ST) {
    int v = blockIdx.x;
    int t = threadIdx.x;
    const float4* row = (const float4*)(ve + (size_t)v * NEMBD);
    float4 f = row[t];
    float s = f.x + f.y + f.z + f.w;
    s += __shfl_down(s, 4, 8);
    s += __shfl_down(s, 2, 8);
    s += __shfl_down(s, 1, 8);
    if ((t & 7) == 0) ST[v * 32 + (t >> 3)] = f2bf_rne(s);
}

// K1b: pack QK A-operand (SA) and PV B-operand (S2) fragment layouts.
// Block = one 32-row chunk c. threads 0-127: SA, 128-255: S2.
__global__ void k_pack(const ushort_t* __restrict__ ST, ushort_t* __restrict__ SA,
                       ushort_t* __restrict__ S2) {
    int c = blockIdx.x;              // 1000
    int t = threadIdx.x;             // 256
    if (t < 128) {
        // SA[(c*128 + tile*64 + lane)*8 + j] = ST[(c*32 + tile*16 + lo)*32 + quad*8 + j]
        int tile = t >> 6, lane = t & 63;
        int quad = lane >> 4, lo = lane & 15;
        uint4 d = *(const uint4*)(ST + ((size_t)(c * 32 + tile * 16 + lo)) * 32 + quad * 8);
        ((uint4*)SA)[c * 128 + t] = d;
    } else {
        // S2[(c*128 + f*64 + lane)*8 + t2*4 + j]  (16x16x16 B-frag: k=quad*4+j)
        int tt = t - 128;
        int f = tt >> 6, l = tt & 63;
        int quad = l >> 4, lo = l & 15;
        uint w[4];
        #pragma unroll
        for (int t2 = 0; t2 < 2; t2++) {
            #pragma unroll
            for (int jj = 0; jj < 2; jj++) {
                ushort_t v0 = ST[(c * 32 + t2 * 16 + quad * 4 + jj * 2 + 0) * 32 + f * 16 + lo];
                ushort_t v1 = ST[(c * 32 + t2 * 16 + quad * 4 + jj * 2 + 1) * 32 + f * 16 + lo];
                w[t2 * 2 + jj] = (uint)v0 | ((uint)v1 << 16);
            }
        }
        ((uint4*)S2)[c * 128 + tt] = make_uint4(w[0], w[1], w[2], w[3]);
    }
}

// K0: q1[i*32+d] = bf16((x[i]·W_ffn[d] + b_ffn[d]) * log2e / max(temps[n],0.1))
__global__ void k_q1(const float* __restrict__ x, const float* __restrict__ W,
                     const float* __restrict__ b, const float* __restrict__ temps,
                     ushort_t* __restrict__ q1) {
    int tid = blockIdx.x * 256 + threadIdx.x;   // 131072
    int i = tid >> 5, d = tid & 31, n = i & 31;
    const float* xr = x + i * 32;
    float s = b[d];
    #pragma unroll
    for (int h = 0; h < 32; h++) s += xr[h] * W[d * 32 + h];
    q1[tid] = f2bf_rne(s * (LOG2E / fmaxf(temps[n], 0.1f)));
}

// K2: flash projection, LDS-free. Grid 2048: p = blk>>6 (vocab split, 32),
// g = blk&63 (q-group) so concurrently-resident blocks share the chunk range.
// 256 thr = 4 waves; wave w owns q-subtile w. No barriers; fragments read
// straight from L1/L2 (SA+S2 = 4 MB, lane-contiguous 1 KB segments).
__launch_bounds__(256, 8)
__global__ void k_proj(const ushort_t* __restrict__ SA, const ushort_t* __restrict__ S2,
                       const ushort_t* __restrict__ q, float* __restrict__ pN,
                       float* __restrict__ pD) {
    int p = blockIdx.x >> 6, g = blockIdx.x & 63;
    int w = threadIdx.x >> 6, lane = threadIdx.x & 63;
    int quad = lane >> 4, lo = lane & 15;

    short8 qf = *(const short8*)(q + ((g * 64 + w * 16 + lo) * 32 + quad * 8));

    float4_t pv0 = (float4_t){0.f, 0.f, 0.f, 0.f};
    float4_t pv1 = (float4_t){0.f, 0.f, 0.f, 0.f};
    float dsum = 0.f;
    const float4_t zero4 = (float4_t){0.f, 0.f, 0.f, 0.f};

    int start = (p * 125) >> 2, end = ((p + 1) * 125) >> 2;  // 31-32 chunks
    const ushort_t* pa = SA + (size_t)start * 1024 + lane * 8;
    const ushort_t* pb = S2 + (size_t)start * 1024 + lane * 8;

    #pragma unroll 2
    for (int c = start; c < end; c++) {
        short8 a0  = *(const short8*)pa;            // v-tile 0 (QK A-frag)
        short8 a1  = *(const short8*)(pa + 512);    // v-tile 1
        short8 sb0 = *(const short8*)pb;            // h 0..15 (PV B-frags)
        short8 sb1 = *(const short8*)(pb + 512);    // h 16..31
        pa += 1024; pb += 1024;
        short4_t b00 = {sb0[0], sb0[1], sb0[2], sb0[3]};
        short4_t b01 = {sb0[4], sb0[5], sb0[6], sb0[7]};
        short4_t b10 = {sb1[0], sb1[1], sb1[2], sb1[3]};
        short4_t b11 = {sb1[4], sb1[5], sb1[6], sb1[7]};

        // logits transposed: D[v][q]; C-layout row=v=quad*4+reg, col=q=lo
        float4_t l0 = __builtin_amdgcn_mfma_f32_16x16x32_bf16(a0, qf, zero4, 0, 0, 0);
        float4_t l1 = __builtin_amdgcn_mfma_f32_16x16x32_bf16(a1, qf, zero4, 0, 0, 0);
        float e0 = __builtin_amdgcn_exp2f(l0[0]);
        float e1 = __builtin_amdgcn_exp2f(l0[1]);
        float e2 = __builtin_amdgcn_exp2f(l0[2]);
        float e3 = __builtin_amdgcn_exp2f(l0[3]);
        float f0 = __builtin_amdgcn_exp2f(l1[0]);
        float f1 = __builtin_amdgcn_exp2f(l1[1]);
        float f2 = __builtin_amdgcn_exp2f(l1[2]);
        float f3 = __builtin_amdgcn_exp2f(l1[3]);
        uint u0 = __builtin_amdgcn_perm(__float_as_uint(e1), __float_as_uint(e0), 0x07060302u);
        uint u1 = __builtin_amdgcn_perm(__float_as_uint(e3), __float_as_uint(e2), 0x07060302u);
        uint u2 = __builtin_amdgcn_perm(__float_as_uint(f1), __float_as_uint(f0), 0x07060302u);
        uint u3 = __builtin_amdgcn_perm(__float_as_uint(f3), __float_as_uint(f2), 0x07060302u);
        // denominator on VALU from the same truncated bf16 values PV consumes
        dsum += __uint_as_float(u0 << 16) + __uint_as_float(u0 & 0xffff0000u)
              + __uint_as_float(u1 << 16) + __uint_as_float(u1 & 0xffff0000u)
              + __uint_as_float(u2 << 16) + __uint_as_float(u2 & 0xffff0000u)
              + __uint_as_float(u3 << 16) + __uint_as_float(u3 & 0xffff0000u);
        union { uint u[2]; short4_t s4; } c0u, c1u;
        c0u.u[0] = u0; c0u.u[1] = u1;
        c1u.u[0] = u2; c1u.u[1] = u3;
        short4_t P0 = c0u.s4, P1 = c1u.s4;
        // PV: out[q][h] += P[q][v] * S[v][h]
        pv0 = __builtin_amdgcn_mfma_f32_16x16x16bf16_1k(P0, b00, pv0, 0, 0, 0);
        pv0 = __builtin_amdgcn_mfma_f32_16x16x16bf16_1k(P1, b01, pv0, 0, 0, 0);
        pv1 = __builtin_amdgcn_mfma_f32_16x16x16bf16_1k(P0, b10, pv1, 0, 0, 0);
        pv1 = __builtin_amdgcn_mfma_f32_16x16x16bf16_1k(P1, b11, pv1, 0, 0, 0);
    }

    // finish denominator: sum over quads (q=lo fixed per lane)
    dsum += __shfl_xor(dsum, 16, 64);
    dsum += __shfl_xor(dsum, 32, 64);

    // direct per-wave epilogue (C-layout of PV: row=q=quad*4+r, col=h=lo)
    int gp = blockIdx.x;   // = p*64+g
    #pragma unroll
    for (int r = 0; r < 4; r++) {
        int ql = w * 16 + quad * 4 + r;
        pN[((size_t)gp * 64 + ql) * 32 + lo]      = pv0[r];
        pN[((size_t)gp * 64 + ql) * 32 + 16 + lo] = pv1[r];
    }
    if (quad == 0) pD[gp * 64 + w * 16 + lo] = dsum;
}

// K3: reduce proj1 partials (32 splits), refinement gate, emit q2 (bf16, pre-scaled).
__global__ void k_refine(const float* __restrict__ pN, const float* __restrict__ pD,
                         const float* __restrict__ x,
                         const float* __restrict__ Wr, const float* __restrict__ br,
                         const float* __restrict__ Wg, const float* __restrict__ bg,
                         const float* __restrict__ temps, ushort_t* __restrict__ q2) {
    int tid = blockIdx.x * 256 + threadIdx.x;   // 131072
    int i = tid >> 5, h = tid & 31, n = i & 31;
    int g = i >> 6, ql = i & 63;
    float N = 0.f, D = 0.f;
    #pragma unroll
    for (int p = 0; p < 32; p++) {
        N += pN[((size_t)(p * 64 + g) * 64 + ql) * 32 + h];
        D += pD[(p * 64 + g) * 64 + ql];
    }
    float vo = N / D;
    const float* xr = x + i * 32;
    float sr = br[h], sg = bg[h];
    #pragma unroll
    for (int h2 = 0; h2 < 32; h2++) {
        sr += xr[h2] * Wr[h * 32 + h2];
        sg += xr[h2] * Wg[h * 32 + h2];
    }
    float ref  = tanhf(sr);
    float gate = 1.f / (1.f + __expf(-sg));
    float refined = vo * (1.f - gate) + ref * gate;
    q2[tid] = f2bf_rne(refined * (LOG2E / fmaxf(temps[n], 0.1f)));
}

// K5: reduce proj2 partials, write final fp32 output.
__global__ void k_final(const float* __restrict__ pN, const float* __restrict__ pD,
                        float* __restrict__ out) {
    int tid = blockIdx.x * 256 + threadIdx.x;   // 131072
    int i = tid >> 5, h = tid & 31;
    int g = i >> 6, ql = i & 63;
    float N = 0.f, D = 0.f;
    #pragma unroll
    for (int p = 0; p < 32; p++) {
        N += pN[((size_t)(p * 64 + g) * 64 + ql) * 32 + h];
        D += pD[(p * 64 + g) * 64 + ql];
    }
    out[tid] = N / D;
}

extern "C" void kernel_launch(void* const* d_in, const int* in_sizes, int n_in,
                              void* d_out, int out_size, void* d_ws, size_t ws_size,
                              hipStream_t stream) {
    const float* x     = (const float*)d_in[0];
    const float* ve    = (const float*)d_in[1];
    const float* Wf    = (const float*)d_in[2];
    const float* bfn   = (const float*)d_in[3];
    const float* temps = (const float*)d_in[4];
    const float* Wr    = (const float*)d_in[5];
    const float* br    = (const float*)d_in[6];
    const float* Wg    = (const float*)d_in[7];
    const float* bg    = (const float*)d_in[8];
    float* out = (float*)d_out;

    char* ws = (char*)d_ws;
    ushort_t* ST = (ushort_t*)ws;                           // 2,048,000 B
    ushort_t* SA = (ushort_t*)(ws + 2048000);               // 2,048,000 B
    ushort_t* S2 = (ushort_t*)(ws + 4096000);               // 2,048,000 B
    ushort_t* q1 = (ushort_t*)(ws + 6144000);               //   262,144 B
    ushort_t* q2 = (ushort_t*)(ws + 6144000 + 262144);      //   262,144 B
    char* base = ws + 6144000 + 2 * 262144;
    float* pNa = (float*)base;                              // 16,777,216 B
    float* pDa = (float*)(base + 16777216);                 //    524,288 B
    float* pNb = (float*)(base + 16777216 + 524288);        // 16,777,216 B
    float* pDb = (float*)(base + 2 * 16777216 + 524288);    //    524,288 B

    k_build_st<<<dim3(VOCAB), dim3(256), 0, stream>>>(ve, ST);
    k_pack<<<dim3(1000), dim3(256), 0, stream>>>(ST, SA, S2);
    k_q1<<<dim3(512), dim3(256), 0, stream>>>(x, Wf, bfn, temps, q1);
    k_proj<<<dim3(2048), dim3(256), 0, stream>>>(SA, S2, q1, pNa, pDa);
    k_refine<<<dim3(512), dim3(256), 0, stream>>>(pNa, pDa, x, Wr, br, Wg, bg, temps, q2);
    k_proj<<<dim3(2048), dim3(256), 0, stream>>>(SA, S2, q2, pNb, pDb);
    k_final<<<dim3(512), dim3(256), 0, stream>>>(pNb, pDb, out);
}

// Round 6
// 271.358 us; speedup vs baseline: 1.0564x; 1.0564x over previous
//
#include <hip/hip_runtime.h>
#include <hip/hip_bf16.h>
#include <cstdint>

typedef unsigned int uint;
typedef unsigned short ushort_t;

typedef __attribute__((ext_vector_type(8))) short short8;
typedef __attribute__((ext_vector_type(4))) short short4_t;
typedef __attribute__((ext_vector_type(4))) float float4_t;

#define NEMBD 1024
#define VOCAB 32000
#define LOG2E 1.4426950408889634f

__device__ __forceinline__ ushort_t f2bf_rne(float f) {
    uint u = __float_as_uint(f);
    u += 0x7fffu + ((u >> 16) & 1u);
    return (ushort_t)(u >> 16);
}

// K1a: ST[v*32+h] = bf16(sum_d ve[v, h*32+d]). Block per vocab row, coalesced.
__global__ void k_build_st(const float* __restrict__ ve, ushort_t* __restrict__ ST) {
    int v = blockIdx.x;
    int t = threadIdx.x;
    const float4* row = (const float4*)(ve + (size_t)v * NEMBD);
    float4 f = row[t];
    float s = f.x + f.y + f.z + f.w;
    s += __shfl_down(s, 4, 8);
    s += __shfl_down(s, 2, 8);
    s += __shfl_down(s, 1, 8);
    if ((t & 7) == 0) ST[v * 32 + (t >> 3)] = f2bf_rne(s);
}

// K1b: pack QK A-operand (SA) and PV B-operand (S2) fragment layouts.
__global__ void k_pack(const ushort_t* __restrict__ ST, ushort_t* __restrict__ SA,
                       ushort_t* __restrict__ S2) {
    int c = blockIdx.x;              // 1000
    int t = threadIdx.x;             // 256
    if (t < 128) {
        int tile = t >> 6, lane = t & 63;
        int quad = lane >> 4, lo = lane & 15;
        uint4 d = *(const uint4*)(ST + ((size_t)(c * 32 + tile * 16 + lo)) * 32 + quad * 8);
        ((uint4*)SA)[c * 128 + t] = d;
    } else {
        int tt = t - 128;
        int f = tt >> 6, l = tt & 63;
        int quad = l >> 4, lo = l & 15;
        uint w[4];
        #pragma unroll
        for (int t2 = 0; t2 < 2; t2++) {
            #pragma unroll
            for (int jj = 0; jj < 2; jj++) {
                ushort_t v0 = ST[(c * 32 + t2 * 16 + quad * 4 + jj * 2 + 0) * 32 + f * 16 + lo];
                ushort_t v1 = ST[(c * 32 + t2 * 16 + quad * 4 + jj * 2 + 1) * 32 + f * 16 + lo];
                w[t2 * 2 + jj] = (uint)v0 | ((uint)v1 << 16);
            }
        }
        ((uint4*)S2)[c * 128 + tt] = make_uint4(w[0], w[1], w[2], w[3]);
    }
}

// K0: q1[i*32+d] = bf16((x[i]·W_ffn[d] + b_ffn[d]) * log2e / max(temps[n],0.1))
__global__ void k_q1(const float* __restrict__ x, const float* __restrict__ W,
                     const float* __restrict__ b, const float* __restrict__ temps,
                     ushort_t* __restrict__ q1) {
    int tid = blockIdx.x * 256 + threadIdx.x;   // 131072
    int i = tid >> 5, d = tid & 31, n = i & 31;
    const float* xr = x + i * 32;
    float s = b[d];
    #pragma unroll
    for (int h = 0; h < 32; h++) s += xr[h] * W[d * 32 + h];
    q1[tid] = f2bf_rne(s * (LOG2E / fmaxf(temps[n], 0.1f)));
}

// K2: flash projection. Grid 1024 = 64 q-groups (g = blk>>4) x 16 splits
// (p = blk&15) -- co-resident blocks on a CU share p (same chunk range).
// 4 waves; each wave covers ALL 64 q-rows (4 subtiles) for its stride-4
// chunk subset -> S loads amortized 4x. Explicit 1-deep prefetch pipeline.
__launch_bounds__(256, 4)
__global__ void k_proj(const ushort_t* __restrict__ SA, const ushort_t* __restrict__ S2,
                       const ushort_t* __restrict__ q, float* __restrict__ pN,
                       float* __restrict__ pD) {
    int g = blockIdx.x >> 4, p = blockIdx.x & 15;
    int w = threadIdx.x >> 6, lane = threadIdx.x & 63;
    int quad = lane >> 4, lo = lane & 15;

    // Q fragments (B-operand of 16x16x32: n=lo (query row), k=quad*8+j)
    short8 qf[4];
    #pragma unroll
    for (int s = 0; s < 4; s++)
        qf[s] = *(const short8*)(q + ((g * 64 + s * 16 + lo) * 32 + quad * 8));

    float4_t pv0[4], pv1[4];
    float dsum[4];
    #pragma unroll
    for (int s = 0; s < 4; s++) {
        pv0[s] = (float4_t){0.f, 0.f, 0.f, 0.f};
        pv1[s] = (float4_t){0.f, 0.f, 0.f, 0.f};
        dsum[s] = 0.f;
    }
    const float4_t zero4 = (float4_t){0.f, 0.f, 0.f, 0.f};

    int start = (p * 125) >> 1, end = ((p + 1) * 125) >> 1;  // 62-63 chunks
    int k = start + w;
    const ushort_t* pa = SA + (size_t)k * 1024 + lane * 8;
    const ushort_t* pb = S2 + (size_t)k * 1024 + lane * 8;
    // prefetch first chunk
    short8 a0n = *(const short8*)pa;
    short8 a1n = *(const short8*)(pa + 512);
    short8 b0n = *(const short8*)pb;
    short8 b1n = *(const short8*)(pb + 512);

    while (true) {
        short8 a0 = a0n, a1 = a1n, s0 = b0n, s1 = b1n;
        k += 4;
        bool more = (k < end);
        if (more) {   // wave-uniform branch; issue next chunk's loads now
            pa += 4096; pb += 4096;
            a0n = *(const short8*)pa;
            a1n = *(const short8*)(pa + 512);
            b0n = *(const short8*)pb;
            b1n = *(const short8*)(pb + 512);
        }
        short4_t b00 = {s0[0], s0[1], s0[2], s0[3]};
        short4_t b01 = {s0[4], s0[5], s0[6], s0[7]};
        short4_t b10 = {s1[0], s1[1], s1[2], s1[3]};
        short4_t b11 = {s1[4], s1[5], s1[6], s1[7]};

        #pragma unroll
        for (int s = 0; s < 4; s++) {
            // logits transposed: D[v][q]; C-layout row=v=quad*4+reg, col=q=lo
            float4_t l0 = __builtin_amdgcn_mfma_f32_16x16x32_bf16(a0, qf[s], zero4, 0, 0, 0);
            float4_t l1 = __builtin_amdgcn_mfma_f32_16x16x32_bf16(a1, qf[s], zero4, 0, 0, 0);
            float e0 = __builtin_amdgcn_exp2f(l0[0]);
            float e1 = __builtin_amdgcn_exp2f(l0[1]);
            float e2 = __builtin_amdgcn_exp2f(l0[2]);
            float e3 = __builtin_amdgcn_exp2f(l0[3]);
            float f0 = __builtin_amdgcn_exp2f(l1[0]);
            float f1 = __builtin_amdgcn_exp2f(l1[1]);
            float f2 = __builtin_amdgcn_exp2f(l1[2]);
            float f3 = __builtin_amdgcn_exp2f(l1[3]);
            uint u0 = __builtin_amdgcn_perm(__float_as_uint(e1), __float_as_uint(e0), 0x07060302u);
            uint u1 = __builtin_amdgcn_perm(__float_as_uint(e3), __float_as_uint(e2), 0x07060302u);
            uint u2 = __builtin_amdgcn_perm(__float_as_uint(f1), __float_as_uint(f0), 0x07060302u);
            uint u3 = __builtin_amdgcn_perm(__float_as_uint(f3), __float_as_uint(f2), 0x07060302u);
            // denominator on VALU from the same truncated bf16 values PV consumes
            dsum[s] += __uint_as_float(u0 << 16) + __uint_as_float(u0 & 0xffff0000u)
                     + __uint_as_float(u1 << 16) + __uint_as_float(u1 & 0xffff0000u)
                     + __uint_as_float(u2 << 16) + __uint_as_float(u2 & 0xffff0000u)
                     + __uint_as_float(u3 << 16) + __uint_as_float(u3 & 0xffff0000u);
            union { uint u[2]; short4_t s4; } c0u, c1u;
            c0u.u[0] = u0; c0u.u[1] = u1;
            c1u.u[0] = u2; c1u.u[1] = u3;
            short4_t P0 = c0u.s4, P1 = c1u.s4;
            // PV: out[q][h] += P[q][v] * S[v][h]
            pv0[s] = __builtin_amdgcn_mfma_f32_16x16x16bf16_1k(P0, b00, pv0[s], 0, 0, 0);
            pv0[s] = __builtin_amdgcn_mfma_f32_16x16x16bf16_1k(P1, b01, pv0[s], 0, 0, 0);
            pv1[s] = __builtin_amdgcn_mfma_f32_16x16x16bf16_1k(P0, b10, pv1[s], 0, 0, 0);
            pv1[s] = __builtin_amdgcn_mfma_f32_16x16x16bf16_1k(P1, b11, pv1[s], 0, 0, 0);
        }
        if (!more) break;
    }

    // finish per-q denominator: sum over quads (q=lo fixed per lane)
    #pragma unroll
    for (int s = 0; s < 4; s++) {
        dsum[s] += __shfl_xor(dsum[s], 16, 64);
        dsum[s] += __shfl_xor(dsum[s], 32, 64);
    }

    // cross-wave reduction (waves covered disjoint chunk subsets)
    __shared__ float red[4][64][9];
    int gp = blockIdx.x;
    for (int s = 0; s < 4; s++) {
        #pragma unroll
        for (int r = 0; r < 4; r++) {
            red[w][lane][r]     = pv0[s][r];
            red[w][lane][4 + r] = pv1[s][r];
        }
        red[w][lane][8] = dsum[s];
        __syncthreads();
        if (w == 0) {
            #pragma unroll
            for (int r = 0; r < 4; r++) {
                float n0 = 0.f, n1 = 0.f;
                #pragma unroll
                for (int wv = 0; wv < 4; wv++) {
                    n0 += red[wv][lane][r];
                    n1 += red[wv][lane][4 + r];
                }
                int ql = s * 16 + quad * 4 + r;
                pN[((size_t)gp * 64 + ql) * 32 + lo]      = n0;
                pN[((size_t)gp * 64 + ql) * 32 + 16 + lo] = n1;
            }
            if (quad == 0) {
                float dd = red[0][lane][8] + red[1][lane][8]
                         + red[2][lane][8] + red[3][lane][8];
                pD[gp * 64 + s * 16 + lo] = dd;
            }
        }
        __syncthreads();
    }
}

// K3: reduce proj1 partials (16 splits), refinement gate, emit q2 (bf16, pre-scaled).
__global__ void k_refine(const float* __restrict__ pN, const float* __restrict__ pD,
                         const float* __restrict__ x,
                         const float* __restrict__ Wr, const float* __restrict__ br,
                         const float* __restrict__ Wg, const float* __restrict__ bg,
                         const float* __restrict__ temps, ushort_t* __restrict__ q2) {
    int tid = blockIdx.x * 256 + threadIdx.x;   // 131072
    int i = tid >> 5, h = tid & 31, n = i & 31;
    int g = i >> 6, ql = i & 63;
    float N = 0.f, D = 0.f;
    #pragma unroll
    for (int p = 0; p < 16; p++) {
        N += pN[((size_t)(g * 16 + p) * 64 + ql) * 32 + h];
        D += pD[(g * 16 + p) * 64 + ql];
    }
    float vo = N / D;
    const float* xr = x + i * 32;
    float sr = br[h], sg = bg[h];
    #pragma unroll
    for (int h2 = 0; h2 < 32; h2++) {
        sr += xr[h2] * Wr[h * 32 + h2];
        sg += xr[h2] * Wg[h * 32 + h2];
    }
    float ref  = tanhf(sr);
    float gate = 1.f / (1.f + __expf(-sg));
    float refined = vo * (1.f - gate) + ref * gate;
    q2[tid] = f2bf_rne(refined * (LOG2E / fmaxf(temps[n], 0.1f)));
}

// K5: reduce proj2 partials, write final fp32 output.
__global__ void k_final(const float* __restrict__ pN, const float* __restrict__ pD,
                        float* __restrict__ out) {
    int tid = blockIdx.x * 256 + threadIdx.x;   // 131072
    int i = tid >> 5, h = tid & 31;
    int g = i >> 6, ql = i & 63;
    float N = 0.f, D = 0.f;
    #pragma unroll
    for (int p = 0; p < 16; p++) {
        N += pN[((size_t)(g * 16 + p) * 64 + ql) * 32 + h];
        D += pD[(g * 16 + p) * 64 + ql];
    }
    out[tid] = N / D;
}

extern "C" void kernel_launch(void* const* d_in, const int* in_sizes, int n_in,
                              void* d_out, int out_size, void* d_ws, size_t ws_size,
                              hipStream_t stream) {
    const float* x     = (const float*)d_in[0];
    const float* ve    = (const float*)d_in[1];
    const float* Wf    = (const float*)d_in[2];
    const float* bfn   = (const float*)d_in[3];
    const float* temps = (const float*)d_in[4];
    const float* Wr    = (const float*)d_in[5];
    const float* br    = (const float*)d_in[6];
    const float* Wg    = (const float*)d_in[7];
    const float* bg    = (const float*)d_in[8];
    float* out = (float*)d_out;

    char* ws = (char*)d_ws;
    ushort_t* ST = (ushort_t*)ws;                           // 2,048,000 B
    ushort_t* SA = (ushort_t*)(ws + 2048000);               // 2,048,000 B
    ushort_t* S2 = (ushort_t*)(ws + 4096000);               // 2,048,000 B
    ushort_t* q1 = (ushort_t*)(ws + 6144000);               //   262,144 B
    ushort_t* q2 = (ushort_t*)(ws + 6144000 + 262144);      //   262,144 B
    char* base = ws + 6144000 + 2 * 262144;
    float* pNa = (float*)base;                              // 8,388,608 B
    float* pDa = (float*)(base + 8388608);                  //   262,144 B
    float* pNb = (float*)(base + 8388608 + 262144);         // 8,388,608 B
    float* pDb = (float*)(base + 2 * 8388608 + 262144);     //   262,144 B

    k_build_st<<<dim3(VOCAB), dim3(256), 0, stream>>>(ve, ST);
    k_pack<<<dim3(1000), dim3(256), 0, stream>>>(ST, SA, S2);
    k_q1<<<dim3(512), dim3(256), 0, stream>>>(x, Wf, bfn, temps, q1);
    k_proj<<<dim3(1024), dim3(256), 0, stream>>>(SA, S2, q1, pNa, pDa);
    k_refine<<<dim3(512), dim3(256), 0, stream>>>(pNa, pDa, x, Wr, br, Wg, bg, temps, q2);
    k_proj<<<dim3(1024), dim3(256), 0, stream>>>(SA, S2, q2, pNb, pDb);
    k_final<<<dim3(512), dim3(256), 0, stream>>>(pNb, pDb, out);
}